// Round 12
// baseline (386.362 us; speedup 1.0000x reference)
//
#include <hip/hip_runtime.h>
#include <stdint.h>

#define SEQ_ 2048
#define DIM_ 1024
#define HD_ 64
#define NH_ 16

typedef __bf16 bf16x8 __attribute__((ext_vector_type(8)));
typedef float f32x4 __attribute__((ext_vector_type(4)));
typedef __attribute__((address_space(1))) unsigned int as1_uint;
typedef __attribute__((address_space(3))) unsigned int as3_uint;

__device__ __forceinline__ unsigned short f2bf(float f) {
  unsigned u = __builtin_bit_cast(unsigned, f);
  u += 0x7fffu + ((u >> 16) & 1u);
  return (unsigned short)(u >> 16);
}
__device__ __forceinline__ float bf2f(unsigned short u) {
  return __builtin_bit_cast(float, ((unsigned)u) << 16);
}
// pack two f32 -> two bf16 (truncate) in ONE v_perm_b32
__device__ __forceinline__ unsigned pk_bf2(float lo, float hi) {
  return __builtin_amdgcn_perm(__builtin_bit_cast(unsigned, hi),
                               __builtin_bit_cast(unsigned, lo), 0x07060302u);
}
// single-instruction 2^x
__device__ __forceinline__ float ex2(float x) {
  float r;
  asm("v_exp_f32 %0, %1" : "=v"(r) : "v"(x));
  return r;
}
// explicit waits: compiler does NOT reliably emit vmcnt before s_barrier for
// cross-backedge global_load_lds deps (R4 race) — we control them manually.
__device__ __forceinline__ void vm_drain() {
  asm volatile("s_waitcnt vmcnt(0)" ::: "memory");
}
// counted wait (T4): allow the newest 4 DMA loads to stay in flight.
// SAFETY: requires >=3 LDS buffers — with 2, the next step reads a buffer
// whose loads may still be in flight.
__device__ __forceinline__ void vm_wait4() {
  asm volatile("s_waitcnt vmcnt(4)" ::: "memory");
}
__device__ __forceinline__ void lgkm_drain() {
  asm volatile("s_waitcnt lgkmcnt(0)" ::: "memory");
}

// async global->LDS, 16B per lane. LDS dest is wave-uniform base + lane*16.
__device__ __forceinline__ void gload_lds16(const void* g, void* l) {
  __builtin_amdgcn_global_load_lds(
      reinterpret_cast<as1_uint*>(reinterpret_cast<uintptr_t>(g)),
      reinterpret_cast<as3_uint*>(
          static_cast<unsigned int>(reinterpret_cast<uintptr_t>(l))),
      16, 0, 0);
}

// ---------------- weight transpose + fp32->bf16 convert: Wt[n][k] = W[k][n]
__global__ __launch_bounds__(256) void transpose_cvt(
    const float* __restrict__ W, unsigned short* __restrict__ Wt, int K, int N) {
  __shared__ float t[32][33];
  const int tx = threadIdx.x & 31, ty = threadIdx.x >> 5;  // ty 0..7
  const int n0 = blockIdx.x * 32, k0 = blockIdx.y * 32;
#pragma unroll
  for (int i = 0; i < 4; i++)
    t[ty + i * 8][tx] = W[(size_t)(k0 + ty + i * 8) * N + n0 + tx];
  __syncthreads();
#pragma unroll
  for (int i = 0; i < 4; i++)
    Wt[(size_t)(n0 + ty + i * 8) * K + k0 + tx] = f2bf(t[tx][ty + i * 8]);
}

// ---------------- rmsnorm over DIM: out = x/max(||x||,eps)*32*g  (bf16)
__global__ __launch_bounds__(256) void rmsnorm_k(
    const float* __restrict__ x, const float* __restrict__ g,
    unsigned short* __restrict__ out) {
  const int row = blockIdx.x;
  const float4* xr = (const float4*)(x + (size_t)row * DIM_);
  float4 v = xr[threadIdx.x];
  float ss = v.x * v.x + v.y * v.y + v.z * v.z + v.w * v.w;
  ss += __shfl_xor(ss, 1);  ss += __shfl_xor(ss, 2);  ss += __shfl_xor(ss, 4);
  ss += __shfl_xor(ss, 8);  ss += __shfl_xor(ss, 16); ss += __shfl_xor(ss, 32);
  __shared__ float red[4];
  if ((threadIdx.x & 63) == 0) red[threadIdx.x >> 6] = ss;
  __syncthreads();
  float tot = red[0] + red[1] + red[2] + red[3];
  float sc = 32.0f * g[0] / fmaxf(sqrtf(tot), 1e-12f);
  unsigned short* orow = out + (size_t)row * DIM_;
  const int b4 = threadIdx.x * 4;
  orow[b4 + 0] = f2bf(v.x * sc);
  orow[b4 + 1] = f2bf(v.y * sc);
  orow[b4 + 2] = f2bf(v.z * sc);
  orow[b4 + 3] = f2bf(v.w * sc);
}

// ---------------- GEMM: C[M,N] = A[M,K]@Bt[N,K]^T, split-K over gridDim.z
// NEW (T4, R11-attn-proven pattern): TRIPLE-buffered BK=32 with 2-step-deep
// prefetch + counted s_waitcnt vmcnt(4) at the per-step barrier — step k+1's
// 4 loads (issued a full K-step earlier) must have landed; step k+2's stay
// in flight. Removes the 300-500cy/step DMA-latency stall that vmcnt(0)
// exposed (GEMM MfmaUtil was 22%). LDS 48 KB -> 3 blocks/CU.
// Chunk-XOR swizzled LDS (0 conflicts, verified); XCD-chunked bijective
// blockIdx swizzle (FETCH 155->~50MB on fc2, R8 win).
// EPI: 0 = bias, bf16 out; 1 = bias + residual, f32 out;
//      2 = bias + gelu, bf16 out; 3 = raw f32 partial at z-offset (no bias)
template <int EPI>
__global__ __launch_bounds__(256, 2) void gemm_bf16(
    const unsigned short* __restrict__ A, const unsigned short* __restrict__ Bt,
    const float* __restrict__ bias, const float* __restrict__ res,
    void* __restrict__ Cout, int M, int N, int K) {
  __shared__ __align__(16) unsigned short As[3][128 * 32];
  __shared__ __align__(16) unsigned short Bs[3][128 * 32];
  const int tid = threadIdx.x;
  const int w = tid >> 6, lane = tid & 63;
  const int wm = w >> 1, wn = w & 1;
  const int quad = lane >> 4, l15 = lane & 15;

  // XCD-chunked bijective swizzle (T1)
  const unsigned gx = gridDim.x, gy = gridDim.y;
  const unsigned nwg = gx * gy * gridDim.z;
  const unsigned p0 = blockIdx.x + gx * (blockIdx.y + gy * blockIdx.z);
  const unsigned lg = (p0 & 7) * (nwg >> 3) + (p0 >> 3);
  const int bn = lg % gx;
  const unsigned t1 = lg / gx;
  const int bm = t1 % gy;
  const int bz = t1 / gy;

  const int Kchunk = K / gridDim.z;
  const int kbeg = bz * Kchunk;

  f32x4 acc[4][4];
#pragma unroll
  for (int i = 0; i < 4; i++)
#pragma unroll
    for (int j = 0; j < 4; j++) acc[i][j] = f32x4{0.f, 0.f, 0.f, 0.f};

  const int r0 = w * 16 + (lane >> 2);
  const int csw = ((lane & 3) ^ ((lane >> 3) & 3)) * 8;
  const unsigned short* gA0 = A + (size_t)(bm * 128 + r0) * K + kbeg + csw;
  const unsigned short* gA1 = gA0 + (size_t)64 * K;
  const unsigned short* gB0 = Bt + (size_t)(bn * 128 + r0) * K + kbeg + csw;
  const unsigned short* gB1 = gB0 + (size_t)64 * K;
  const int lofs = w * 512;

  auto stage = [&](int buf) {
    gload_lds16(gA0, &As[buf][lofs]);
    gload_lds16(gA1, &As[buf][2048 + lofs]);
    gload_lds16(gB0, &Bs[buf][lofs]);
    gload_lds16(gB1, &Bs[buf][2048 + lofs]);
    gA0 += 32; gA1 += 32; gB0 += 32; gB1 += 32;
  };

  const int qsw = (quad ^ ((l15 >> 1) & 3)) * 8;

  // prologue: stage steps 0 and 1 (niter >= 8 for all shapes here)
  stage(0);
  stage(1);
  vm_wait4();  // step 0's 4 (oldest) landed; step 1's may fly
  __syncthreads();
  const int niter = Kchunk / 32;
  int cur = 0;
  for (int kk = 0; kk < niter; kk++) {
    const bool more = (kk + 2 < niter);
    if (more) {  // issue step kk+2 into the buffer freed at step kk-1
      int nb = cur + 2; if (nb >= 3) nb -= 3;
      stage(nb);
    }
    bf16x8 af[4], bfr[4];
#pragma unroll
    for (int i = 0; i < 4; i++) {
      af[i]  = *(const bf16x8*)&As[cur][(wm * 64 + i * 16 + l15) * 32 + qsw];
      bfr[i] = *(const bf16x8*)&Bs[cur][(wn * 64 + i * 16 + l15) * 32 + qsw];
    }
#pragma unroll
    for (int i = 0; i < 4; i++)
#pragma unroll
      for (int j = 0; j < 4; j++)
        acc[i][j] = __builtin_amdgcn_mfma_f32_16x16x32_bf16(af[i], bfr[j], acc[i][j], 0, 0, 0);
    // counted wait: step kk+1's loads landed; tail drains fully
    if (more) vm_wait4(); else vm_drain();
    __syncthreads();
    cur = (cur == 2) ? 0 : cur + 1;
  }

  const int rowb = bm * 128 + wm * 64;
  const int colb = bn * 128 + wn * 64;
  float* Cz = (float*)Cout + (size_t)bz * M * N;  // EPI3 partial slab
  const float kg1 = -2.0f * 1.4426950408889634f * 0.7978845608028654f;
  const float kg2 = kg1 * 0.044715f;
#pragma unroll
  for (int i = 0; i < 4; i++) {
#pragma unroll
    for (int j = 0; j < 4; j++) {
      const int col = colb + j * 16 + l15;
      const float bv = (EPI == 3) ? 0.0f : bias[col];
#pragma unroll
      for (int r = 0; r < 4; r++) {
        const int row = rowb + i * 16 + quad * 4 + r;
        const size_t idx = (size_t)row * N + col;
        float v = acc[i][j][r] + bv;
        if (EPI == 0) {
          ((unsigned short*)Cout)[idx] = f2bf(v);
        } else if (EPI == 1) {
          ((float*)Cout)[idx] = v + res[idx];
        } else if (EPI == 2) {
          const float u = v * (kg1 + kg2 * v * v);
          const float g = v * __builtin_amdgcn_rcpf(1.0f + ex2(u));
          ((unsigned short*)Cout)[idx] = f2bf(g);
        } else {
          Cz[idx] = v;
        }
      }
    }
  }
}

// ---------------- split-K reduce: out = res + bias + sum_z part[z]
__global__ __launch_bounds__(256) void reduce_splitk(
    const float* __restrict__ part, int S, const float* __restrict__ res,
    const float* __restrict__ bias, float* __restrict__ out, int N, size_t MN) {
  const size_t n4 = MN >> 2;
  const size_t i = (size_t)blockIdx.x * 256 + threadIdx.x;
  if (i >= n4) return;
  float4 a = ((const float4*)res)[i];
  float4 b = ((const float4*)bias)[i % (size_t)(N >> 2)];
  float sx = a.x + b.x, sy = a.y + b.y, sz = a.z + b.z, sw = a.w + b.w;
  for (int z = 0; z < S; z++) {
    float4 p = ((const float4*)part)[z * n4 + i];
    sx += p.x; sy += p.y; sz += p.z; sw += p.w;
  }
  ((float4*)out)[i] = make_float4(sx, sy, sz, sw);
}

// ---------------- qkv postprocess (bf16 in): per-head L2 norm of q,k; v transposed
// Q additionally pre-scaled by log2(e) so attn's softmax can use raw v_exp_f32.
__global__ __launch_bounds__(256) void qkv_post(
    const unsigned short* __restrict__ qkv, const float* __restrict__ gq,
    const float* __restrict__ gk, unsigned short* __restrict__ Qs,
    unsigned short* __restrict__ Ks, unsigned short* __restrict__ VT) {
  const int item = blockIdx.x * 4 + (threadIdx.x >> 6);
  const int lane = threadIdx.x & 63;
  const int h = item & 15;
  const int rn = item >> 4;  // b*SEQ+n
  const int b = rn >> 11, n = rn & 2047;
  const unsigned short* base = qkv + (size_t)rn * 3072 + h * 64;
  const float qv = bf2f(base[lane]);
  const float kv = bf2f(base[1024 + lane]);
  const float vv = bf2f(base[2048 + lane]);
  float sq = qv * qv, sk = kv * kv;
  sq += __shfl_xor(sq, 1);  sk += __shfl_xor(sk, 1);
  sq += __shfl_xor(sq, 2);  sk += __shfl_xor(sk, 2);
  sq += __shfl_xor(sq, 4);  sk += __shfl_xor(sk, 4);
  sq += __shfl_xor(sq, 8);  sk += __shfl_xor(sk, 8);
  sq += __shfl_xor(sq, 16); sk += __shfl_xor(sk, 16);
  sq += __shfl_xor(sq, 32); sk += __shfl_xor(sk, 32);
  const float qs = qv / fmaxf(sqrtf(sq), 1e-12f) * (1.4426950408889634f * gq[0]);
  const float ks = kv / fmaxf(sqrtf(sk), 1e-12f) * (8.0f * gk[0]);
  const int bh = b * 16 + h;
  Qs[((size_t)bh * SEQ_ + n) * HD_ + lane] = f2bf(qs);
  Ks[((size_t)bh * SEQ_ + n) * HD_ + lane] = f2bf(ks);
  VT[((size_t)bh * HD_ + lane) * SEQ_ + n] = f2bf(vv);
}

// ---------------- flash attention: 32 q-rows/wave, direct O write (R8 struct).
// T4: TRIPLE-buffered K/V with 2-tile-deep prefetch + counted vmcnt(4)
// at the per-tile barrier (R11-verified, 59.0->56.6us). LDS 64 KB.
// XOR chunk-swizzled K/V/P; setprio around MFMA.
__global__ __launch_bounds__(256) void attn_fwd(
    const unsigned short* __restrict__ Qs, const unsigned short* __restrict__ Ks,
    const unsigned short* __restrict__ VT, const float* __restrict__ gq,
    const float* __restrict__ gk, unsigned short* __restrict__ O) {
  __shared__ __align__(16) unsigned short Kl[3][2][64][32];  // [buf][d-half][key][chunk]
  __shared__ __align__(16) unsigned short Vl[3][2][64][32];  // [buf][key-half][d][chunk]
  __shared__ __align__(16) unsigned short Pl[4][2][16 * 64]; // [wave][q16][q][key]
  const int bh = blockIdx.x, qt = blockIdx.y;
  const int w = threadIdx.x >> 6, lane = threadIdx.x & 63;
  const int quad = lane >> 4, l15 = lane & 15;
  const float M2 = 8.0f * fabsf(gq[0] * gk[0]) * 1.4426950408889634f;
  const f32x4 cin = {-M2, -M2, -M2, -M2};
  const unsigned short* Qb = Qs + (size_t)bh * SEQ_ * HD_;
  const unsigned short* Kb = Ks + (size_t)bh * SEQ_ * HD_;
  const unsigned short* Vb = VT + (size_t)bh * HD_ * SEQ_;
  const int q0 = qt * 128 + w * 32;
  bf16x8 qa[2][2];
#pragma unroll
  for (int q16 = 0; q16 < 2; q16++) {
    qa[q16][0] = *(const bf16x8*)&Qb[(q0 + q16 * 16 + l15) * HD_ + quad * 8];
    qa[q16][1] = *(const bf16x8*)&Qb[(q0 + q16 * 16 + l15) * HD_ + 32 + quad * 8];
  }

  const int csw = ((lane & 3) ^ ((lane >> 3) & 3)) * 8;
  const unsigned short* gsrc[4];
  unsigned short* ldst[4];  // buffer-0 base; buffer b at +b*4096 shorts
  int gstep[4];
#pragma unroll
  for (int i = 0; i < 4; i++) {
    const int idx = w * 4 + i;
    if (idx < 8) {
      const int kc = idx >> 2, kh = idx & 3;
      ldst[i] = &Kl[0][kc][kh * 16][0];
      gsrc[i] = &Kb[(size_t)(kh * 16 + (lane >> 2)) * HD_ + kc * 32 + csw];
      gstep[i] = 64 * HD_;
    } else {
      const int j = idx - 8;
      const int kc = j >> 2, dh = j & 3;
      ldst[i] = &Vl[0][kc][dh * 16][0];
      gsrc[i] = &Vb[(size_t)(dh * 16 + (lane >> 2)) * SEQ_ + kc * 32 + csw];
      gstep[i] = 64;
    }
  }

  f32x4 o[2][4];
  float lacc[2] = {0.0f, 0.0f};
#pragma unroll
  for (int q16 = 0; q16 < 2; q16++)
#pragma unroll
    for (int c = 0; c < 4; c++) o[q16][c] = f32x4{0.f, 0.f, 0.f, 0.f};
  const int qsw = (quad ^ ((l15 >> 1) & 3)) * 8;
  const int psw = l15 & 7;

  const int NT = SEQ_ / 64;
  // prologue: stage tiles 0 and 1 into bufs 0 and 1
#pragma unroll
  for (int i = 0; i < 4; i++) {
    gload_lds16(gsrc[i], ldst[i]);
    gsrc[i] += gstep[i];
  }
#pragma unroll
  for (int i = 0; i < 4; i++) {
    gload_lds16(gsrc[i], ldst[i] + 4096);
    gsrc[i] += gstep[i];
  }
  vm_wait4();  // tile 0 (oldest 4) landed; tile 1's may fly
  __syncthreads();

  int cur = 0;
  for (int kt = 0; kt < NT; kt++) {
    const bool more = (kt + 2 < NT);
    if (more) {
      int nb = cur + 2; if (nb >= 3) nb -= 3;
      const int nofs = nb * 4096;
#pragma unroll
      for (int i = 0; i < 4; i++) {
        gload_lds16(gsrc[i], ldst[i] + nofs);
        gsrc[i] += gstep[i];
      }
    }
    const unsigned short* K0 = &Kl[cur][0][0][0];
    const unsigned short* K1 = &Kl[cur][1][0][0];
    const unsigned short* V0 = &Vl[cur][0][0][0];
    const unsigned short* V1 = &Vl[cur][1][0][0];
    // S^T[key][q] (pre-shifted by -M2), both q16 sub-blocks share K-frags
    f32x4 st[2][4];
    __builtin_amdgcn_s_setprio(1);
#pragma unroll
    for (int kn = 0; kn < 4; kn++) {
      const bf16x8 kf0 = *(const bf16x8*)&K0[(kn * 16 + l15) * 32 + qsw];
      const bf16x8 kf1 = *(const bf16x8*)&K1[(kn * 16 + l15) * 32 + qsw];
      st[0][kn] = __builtin_amdgcn_mfma_f32_16x16x32_bf16(kf0, qa[0][0], cin, 0, 0, 0);
      st[0][kn] = __builtin_amdgcn_mfma_f32_16x16x32_bf16(kf1, qa[0][1], st[0][kn], 0, 0, 0);
      st[1][kn] = __builtin_amdgcn_mfma_f32_16x16x32_bf16(kf0, qa[1][0], cin, 0, 0, 0);
      st[1][kn] = __builtin_amdgcn_mfma_f32_16x16x32_bf16(kf1, qa[1][1], st[1][kn], 0, 0, 0);
    }
    __builtin_amdgcn_s_setprio(0);
    // softmax numerators into per-wave dual P buffers
#pragma unroll
    for (int q16 = 0; q16 < 2; q16++) {
      unsigned short* Pw = &Pl[w][q16][0];
#pragma unroll
      for (int kn = 0; kn < 4; kn++) {
        const float p0 = ex2(st[q16][kn][0]);
        const float p1 = ex2(st[q16][kn][1]);
        const float p2 = ex2(st[q16][kn][2]);
        const float p3 = ex2(st[q16][kn][3]);
        lacc[q16] += (p0 + p1) + (p2 + p3);
        uint2 pk;
        pk.x = pk_bf2(p0, p1);
        pk.y = pk_bf2(p2, p3);
        *(uint2*)&Pw[l15 * 64 + (((kn * 2 + (quad >> 1)) ^ psw) * 8) + (quad & 1) * 4] = pk;
      }
    }
    lgkm_drain();
    bf16x8 pa[2][2];
#pragma unroll
    for (int q16 = 0; q16 < 2; q16++) {
      pa[q16][0] = *(const bf16x8*)&Pl[w][q16][l15 * 64 + ((quad ^ psw) * 8)];
      pa[q16][1] = *(const bf16x8*)&Pl[w][q16][l15 * 64 + (((4 + quad) ^ psw) * 8)];
    }
    __builtin_amdgcn_s_setprio(1);
#pragma unroll
    for (int c = 0; c < 4; c++) {
      const bf16x8 vf0 = *(const bf16x8*)&V0[(c * 16 + l15) * 32 + qsw];
      const bf16x8 vf1 = *(const bf16x8*)&V1[(c * 16 + l15) * 32 + qsw];
      o[0][c] = __builtin_amdgcn_mfma_f32_16x16x32_bf16(pa[0][0], vf0, o[0][c], 0, 0, 0);
      o[0][c] = __builtin_amdgcn_mfma_f32_16x16x32_bf16(pa[0][1], vf1, o[0][c], 0, 0, 0);
      o[1][c] = __builtin_amdgcn_mfma_f32_16x16x32_bf16(pa[1][0], vf0, o[1][c], 0, 0, 0);
      o[1][c] = __builtin_amdgcn_mfma_f32_16x16x32_bf16(pa[1][1], vf1, o[1][c], 0, 0, 0);
    }
    __builtin_amdgcn_s_setprio(0);
    if (more) vm_wait4(); else vm_drain();
    __syncthreads();
    cur = (cur == 2) ? 0 : cur + 1;
  }

  const int b = bh >> 4, h = bh & 15;
#pragma unroll
  for (int q16 = 0; q16 < 2; q16++) {
    float l = lacc[q16];
    l += __shfl_xor(l, 16);
    l += __shfl_xor(l, 32);
    const float linv = 1.0f / l;
    float lr[4];
#pragma unroll
    for (int r = 0; r < 4; r++) lr[r] = __shfl(linv, quad * 4 + r);
#pragma unroll
    for (int c = 0; c < 4; c++)
#pragma unroll
      for (int r = 0; r < 4; r++) {
        const int row = q0 + q16 * 16 + quad * 4 + r;
        O[((size_t)(b * SEQ_ + row)) * DIM_ + h * 64 + c * 16 + l15] =
            f2bf(o[q16][c][r] * lr[r]);
      }
  }
}

extern "C" void kernel_launch(void* const* d_in, const int* in_sizes, int n_in,
                              void* d_out, int out_size, void* d_ws, size_t ws_size,
                              hipStream_t stream) {
  const float* x      = (const float*)d_in[0];
  const float* w_qkv  = (const float*)d_in[1];
  const float* b_qkv  = (const float*)d_in[2];
  const float* w_proj = (const float*)d_in[3];
  const float* b_proj = (const float*)d_in[4];
  const float* g1     = (const float*)d_in[5];
  const float* g2     = (const float*)d_in[6];
  const float* gq     = (const float*)d_in[7];
  const float* gk     = (const float*)d_in[8];
  const float* w_fc1  = (const float*)d_in[9];
  const float* b_fc1  = (const float*)d_in[10];
  const float* w_fc2  = (const float*)d_in[11];
  const float* b_fc2  = (const float*)d_in[12];
  float* out = (float*)d_out;

  char* p = (char*)d_ws;
  auto alloc = [&](size_t bytes) {
    char* r = p;
    p += (bytes + 255) & ~(size_t)255;
    return r;
  };
  const size_t MB = 1ull << 20;
  unsigned short* wqkvT  = (unsigned short*)alloc(3072ull * 1024 * 2);
  unsigned short* wprojT = (unsigned short*)alloc(1024ull * 1024 * 2);
  unsigned short* wfc1T  = (unsigned short*)alloc(4096ull * 1024 * 2);
  unsigned short* wfc2T  = (unsigned short*)alloc(1024ull * 4096 * 2);
  unsigned short* h1     = (unsigned short*)alloc(4096ull * 1024 * 2);  // also Obuf
  unsigned short* QsB = (unsigned short*)alloc(32ull * SEQ_ * HD_ * 2);
  unsigned short* KsB = (unsigned short*)alloc(32ull * SEQ_ * HD_ * 2);
  unsigned short* VTB = (unsigned short*)alloc(32ull * SEQ_ * HD_ * 2);
  float* x2 = (float*)alloc(4096ull * 1024 * 4);
  unsigned short* h2 = (unsigned short*)alloc(4096ull * 1024 * 2);
  char* big = p;
  const size_t rem = ws_size - (size_t)(p - (char*)d_ws);
  unsigned short* qkvb = (unsigned short*)big;
  unsigned short* h3   = (unsigned short*)big;
  float* proj_part = (float*)big;
  float* fc2_part  = (float*)(big + 32 * MB);
  const int S_pr  = rem >= 64 * MB ? 2 : 1;
  const int S_fc2 = rem >= 96 * MB ? 4 : (rem >= 64 * MB ? 2 : 1);
  unsigned short* Obuf = h1;
  const size_t MN = 4096ull * 1024;

  transpose_cvt<<<dim3(3072 / 32, 1024 / 32), 256, 0, stream>>>(w_qkv, wqkvT, 1024, 3072);
  transpose_cvt<<<dim3(1024 / 32, 1024 / 32), 256, 0, stream>>>(w_proj, wprojT, 1024, 1024);
  transpose_cvt<<<dim3(4096 / 32, 1024 / 32), 256, 0, stream>>>(w_fc1, wfc1T, 1024, 4096);
  transpose_cvt<<<dim3(1024 / 32, 4096 / 32), 256, 0, stream>>>(w_fc2, wfc2T, 4096, 1024);
  rmsnorm_k<<<4096, 256, 0, stream>>>(x, g1, h1);
  gemm_bf16<0><<<dim3(3072 / 128, 4096 / 128), 256, 0, stream>>>(
      h1, wqkvT, b_qkv, nullptr, qkvb, 4096, 3072, 1024);
  qkv_post<<<16384, 256, 0, stream>>>(qkvb, gq, gk, QsB, KsB, VTB);
  attn_fwd<<<dim3(32, 16), 256, 0, stream>>>(QsB, KsB, VTB, gq, gk, Obuf);
  if (S_pr > 1) {
    gemm_bf16<3><<<dim3(1024 / 128, 4096 / 128, S_pr), 256, 0, stream>>>(
        Obuf, wprojT, b_proj, nullptr, proj_part, 4096, 1024, 1024);
    reduce_splitk<<<(MN / 4 + 255) / 256, 256, 0, stream>>>(
        proj_part, S_pr, x, b_proj, x2, 1024, MN);
  } else {
    gemm_bf16<1><<<dim3(1024 / 128, 4096 / 128), 256, 0, stream>>>(
        Obuf, wprojT, b_proj, x, x2, 4096, 1024, 1024);
  }
  rmsnorm_k<<<4096, 256, 0, stream>>>(x2, g2, h2);
  gemm_bf16<2><<<dim3(4096 / 128, 4096 / 128), 256, 0, stream>>>(
      h2, wfc1T, b_fc1, nullptr, h3, 4096, 4096, 1024);
  if (S_fc2 > 1) {
    gemm_bf16<3><<<dim3(1024 / 128, 4096 / 128, S_fc2), 256, 0, stream>>>(
        h3, wfc2T, b_fc2, nullptr, fc2_part, 4096, 1024, 4096);
    reduce_splitk<<<(MN / 4 + 255) / 256, 256, 0, stream>>>(
        fc2_part, S_fc2, x2, b_fc2, out, 1024, MN);
  } else {
    gemm_bf16<1><<<dim3(1024 / 128, 4096 / 128), 256, 0, stream>>>(
        h3, wfc2T, b_fc2, x2, out, 4096, 1024, 4096);
  }
}

// Round 13
// 362.320 us; speedup vs baseline: 1.0664x; 1.0664x over previous
//
#include <hip/hip_runtime.h>
#include <stdint.h>

#define SEQ_ 2048
#define DIM_ 1024
#define HD_ 64
#define NH_ 16

typedef __bf16 bf16x8 __attribute__((ext_vector_type(8)));
typedef float f32x4 __attribute__((ext_vector_type(4)));
typedef __attribute__((address_space(1))) unsigned int as1_uint;
typedef __attribute__((address_space(3))) unsigned int as3_uint;

__device__ __forceinline__ unsigned short f2bf(float f) {
  unsigned u = __builtin_bit_cast(unsigned, f);
  u += 0x7fffu + ((u >> 16) & 1u);
  return (unsigned short)(u >> 16);
}
__device__ __forceinline__ float bf2f(unsigned short u) {
  return __builtin_bit_cast(float, ((unsigned)u) << 16);
}
// pack two f32 -> two bf16 (truncate) in ONE v_perm_b32
__device__ __forceinline__ unsigned pk_bf2(float lo, float hi) {
  return __builtin_amdgcn_perm(__builtin_bit_cast(unsigned, hi),
                               __builtin_bit_cast(unsigned, lo), 0x07060302u);
}
// single-instruction 2^x
__device__ __forceinline__ float ex2(float x) {
  float r;
  asm("v_exp_f32 %0, %1" : "=v"(r) : "v"(x));
  return r;
}
// explicit waits: compiler does NOT reliably emit vmcnt before s_barrier for
// cross-backedge global_load_lds deps (R4 race) — we control them manually.
__device__ __forceinline__ void vm_drain() {
  asm volatile("s_waitcnt vmcnt(0)" ::: "memory");
}
// counted wait (T4): allow the newest 4 DMA loads to stay in flight.
// REGIME NOTE (R12 lesson): helps only low-occupancy serial-chain kernels
// (attn, 2 blocks/CU); REGRESSES the 2-phase GEMM (LDS cost kills the
// cross-block TLP that was already hiding the drain).
__device__ __forceinline__ void vm_wait4() {
  asm volatile("s_waitcnt vmcnt(4)" ::: "memory");
}
__device__ __forceinline__ void lgkm_drain() {
  asm volatile("s_waitcnt lgkmcnt(0)" ::: "memory");
}

// async global->LDS, 16B per lane. LDS dest is wave-uniform base + lane*16.
__device__ __forceinline__ void gload_lds16(const void* g, void* l) {
  __builtin_amdgcn_global_load_lds(
      reinterpret_cast<as1_uint*>(reinterpret_cast<uintptr_t>(g)),
      reinterpret_cast<as3_uint*>(
          static_cast<unsigned int>(reinterpret_cast<uintptr_t>(l))),
      16, 0, 0);
}

// ---------------- weight transpose + fp32->bf16 convert: Wt[n][k] = W[k][n]
__global__ __launch_bounds__(256) void transpose_cvt(
    const float* __restrict__ W, unsigned short* __restrict__ Wt, int K, int N) {
  __shared__ float t[32][33];
  const int tx = threadIdx.x & 31, ty = threadIdx.x >> 5;  // ty 0..7
  const int n0 = blockIdx.x * 32, k0 = blockIdx.y * 32;
#pragma unroll
  for (int i = 0; i < 4; i++)
    t[ty + i * 8][tx] = W[(size_t)(k0 + ty + i * 8) * N + n0 + tx];
  __syncthreads();
#pragma unroll
  for (int i = 0; i < 4; i++)
    Wt[(size_t)(n0 + ty + i * 8) * K + k0 + tx] = f2bf(t[tx][ty + i * 8]);
}

// ---------------- rmsnorm over DIM: out = x/max(||x||,eps)*32*g  (bf16)
__global__ __launch_bounds__(256) void rmsnorm_k(
    const float* __restrict__ x, const float* __restrict__ g,
    unsigned short* __restrict__ out) {
  const int row = blockIdx.x;
  const float4* xr = (const float4*)(x + (size_t)row * DIM_);
  float4 v = xr[threadIdx.x];
  float ss = v.x * v.x + v.y * v.y + v.z * v.z + v.w * v.w;
  ss += __shfl_xor(ss, 1);  ss += __shfl_xor(ss, 2);  ss += __shfl_xor(ss, 4);
  ss += __shfl_xor(ss, 8);  ss += __shfl_xor(ss, 16); ss += __shfl_xor(ss, 32);
  __shared__ float red[4];
  if ((threadIdx.x & 63) == 0) red[threadIdx.x >> 6] = ss;
  __syncthreads();
  float tot = red[0] + red[1] + red[2] + red[3];
  float sc = 32.0f * g[0] / fmaxf(sqrtf(tot), 1e-12f);
  unsigned short* orow = out + (size_t)row * DIM_;
  const int b4 = threadIdx.x * 4;
  orow[b4 + 0] = f2bf(v.x * sc);
  orow[b4 + 1] = f2bf(v.y * sc);
  orow[b4 + 2] = f2bf(v.z * sc);
  orow[b4 + 3] = f2bf(v.w * sc);
}

// ---------------- GEMM: C[M,N] = A[M,K]@Bt[N,K]^T, split-K over gridDim.z
// R11-PROVEN config: BK=32 DOUBLE-buffer (32 KB LDS -> ~5 blocks/CU capacity;
// cross-block TLP hides the drain — R12 proved deeper pipelines regress here),
// chunk-XOR swizzled LDS (0 conflicts), issue-early staging + explicit
// vmcnt(0) drain + ONE barrier per K-step, XCD-chunked bijective blockIdx
// swizzle (FETCH 155->~70MB on fc2, R8 win).
// EPI: 0 = bias, bf16 out; 1 = bias + residual, f32 out;
//      2 = bias + gelu, bf16 out; 3 = raw f32 partial at z-offset (no bias)
template <int EPI>
__global__ __launch_bounds__(256, 2) void gemm_bf16(
    const unsigned short* __restrict__ A, const unsigned short* __restrict__ Bt,
    const float* __restrict__ bias, const float* __restrict__ res,
    void* __restrict__ Cout, int M, int N, int K) {
  __shared__ __align__(16) unsigned short As[2][128 * 32];
  __shared__ __align__(16) unsigned short Bs[2][128 * 32];
  const int tid = threadIdx.x;
  const int w = tid >> 6, lane = tid & 63;
  const int wm = w >> 1, wn = w & 1;
  const int quad = lane >> 4, l15 = lane & 15;

  // XCD-chunked bijective swizzle (T1)
  const unsigned gx = gridDim.x, gy = gridDim.y;
  const unsigned nwg = gx * gy * gridDim.z;
  const unsigned p0 = blockIdx.x + gx * (blockIdx.y + gy * blockIdx.z);
  const unsigned lg = (p0 & 7) * (nwg >> 3) + (p0 >> 3);
  const int bn = lg % gx;
  const unsigned t1 = lg / gx;
  const int bm = t1 % gy;
  const int bz = t1 / gy;

  const int Kchunk = K / gridDim.z;
  const int kbeg = bz * Kchunk;

  f32x4 acc[4][4];
#pragma unroll
  for (int i = 0; i < 4; i++)
#pragma unroll
    for (int j = 0; j < 4; j++) acc[i][j] = f32x4{0.f, 0.f, 0.f, 0.f};

  const int r0 = w * 16 + (lane >> 2);
  const int csw = ((lane & 3) ^ ((lane >> 3) & 3)) * 8;
  const unsigned short* gA0 = A + (size_t)(bm * 128 + r0) * K + kbeg + csw;
  const unsigned short* gA1 = gA0 + (size_t)64 * K;
  const unsigned short* gB0 = Bt + (size_t)(bn * 128 + r0) * K + kbeg + csw;
  const unsigned short* gB1 = gB0 + (size_t)64 * K;
  const int lofs = w * 512;

  auto stage = [&](int buf) {
    gload_lds16(gA0, &As[buf][lofs]);
    gload_lds16(gA1, &As[buf][2048 + lofs]);
    gload_lds16(gB0, &Bs[buf][lofs]);
    gload_lds16(gB1, &Bs[buf][2048 + lofs]);
    gA0 += 32; gA1 += 32; gB0 += 32; gB1 += 32;
  };

  const int qsw = (quad ^ ((l15 >> 1) & 3)) * 8;

  stage(0);
  vm_drain();
  __syncthreads();
  const int niter = Kchunk / 32;
  for (int kk = 0; kk < niter; kk++) {
    const int cur = kk & 1;
    if (kk + 1 < niter) stage(cur ^ 1);  // issue-early into other buffer
    bf16x8 af[4], bfr[4];
#pragma unroll
    for (int i = 0; i < 4; i++) {
      af[i]  = *(const bf16x8*)&As[cur][(wm * 64 + i * 16 + l15) * 32 + qsw];
      bfr[i] = *(const bf16x8*)&Bs[cur][(wn * 64 + i * 16 + l15) * 32 + qsw];
    }
#pragma unroll
    for (int i = 0; i < 4; i++)
#pragma unroll
      for (int j = 0; j < 4; j++)
        acc[i][j] = __builtin_amdgcn_mfma_f32_16x16x32_bf16(af[i], bfr[j], acc[i][j], 0, 0, 0);
    vm_drain();
    __syncthreads();
  }

  const int rowb = bm * 128 + wm * 64;
  const int colb = bn * 128 + wn * 64;
  float* Cz = (float*)Cout + (size_t)bz * M * N;  // EPI3 partial slab
  const float kg1 = -2.0f * 1.4426950408889634f * 0.7978845608028654f;
  const float kg2 = kg1 * 0.044715f;
#pragma unroll
  for (int i = 0; i < 4; i++) {
#pragma unroll
    for (int j = 0; j < 4; j++) {
      const int col = colb + j * 16 + l15;
      const float bv = (EPI == 3) ? 0.0f : bias[col];
#pragma unroll
      for (int r = 0; r < 4; r++) {
        const int row = rowb + i * 16 + quad * 4 + r;
        const size_t idx = (size_t)row * N + col;
        float v = acc[i][j][r] + bv;
        if (EPI == 0) {
          ((unsigned short*)Cout)[idx] = f2bf(v);
        } else if (EPI == 1) {
          ((float*)Cout)[idx] = v + res[idx];
        } else if (EPI == 2) {
          const float u = v * (kg1 + kg2 * v * v);
          const float g = v * __builtin_amdgcn_rcpf(1.0f + ex2(u));
          ((unsigned short*)Cout)[idx] = f2bf(g);
        } else {
          Cz[idx] = v;
        }
      }
    }
  }
}

// ---------------- split-K reduce: out = res + bias + sum_z part[z]
__global__ __launch_bounds__(256) void reduce_splitk(
    const float* __restrict__ part, int S, const float* __restrict__ res,
    const float* __restrict__ bias, float* __restrict__ out, int N, size_t MN) {
  const size_t n4 = MN >> 2;
  const size_t i = (size_t)blockIdx.x * 256 + threadIdx.x;
  if (i >= n4) return;
  float4 a = ((const float4*)res)[i];
  float4 b = ((const float4*)bias)[i % (size_t)(N >> 2)];
  float sx = a.x + b.x, sy = a.y + b.y, sz = a.z + b.z, sw = a.w + b.w;
  for (int z = 0; z < S; z++) {
    float4 p = ((const float4*)part)[z * n4 + i];
    sx += p.x; sy += p.y; sz += p.z; sw += p.w;
  }
  ((float4*)out)[i] = make_float4(sx, sy, sz, sw);
}

// ---------------- qkv postprocess: per-head L2 norm of q,k; V transposed.
// NEW: block = (bh, 64-n tile); V goes through an LDS tile and is written
// TRANSPOSED with lane = n -> coalesced 128B rows. (Old version wrote
// VT[d][n] with lane = d: 64-way scatter, 64 transactions per wave.)
// Q pre-scaled by log2(e) so attn's softmax is a raw v_exp_f32.
__global__ __launch_bounds__(256) void qkv_post(
    const unsigned short* __restrict__ qkv, const float* __restrict__ gq,
    const float* __restrict__ gk, unsigned short* __restrict__ Qs,
    unsigned short* __restrict__ Ks, unsigned short* __restrict__ VT) {
  __shared__ unsigned short vt[64][66];
  const int bh = blockIdx.x;  // b*16+h
  const int n0 = blockIdx.y * 64;
  const int b = bh >> 4, h = bh & 15;
  const int w = threadIdx.x >> 6, lane = threadIdx.x & 63;
  const float qsc = 1.4426950408889634f * gq[0];
  const float ksc = 8.0f * gk[0];
  for (int i = 0; i < 16; i++) {
    const int n = n0 + w * 16 + i;
    const unsigned short* base = qkv + (size_t)(b * SEQ_ + n) * 3072 + h * 64;
    const float qv = bf2f(base[lane]);
    const float kv = bf2f(base[1024 + lane]);
    const float vv = bf2f(base[2048 + lane]);
    float sq = qv * qv, sk = kv * kv;
    sq += __shfl_xor(sq, 1);  sk += __shfl_xor(sk, 1);
    sq += __shfl_xor(sq, 2);  sk += __shfl_xor(sk, 2);
    sq += __shfl_xor(sq, 4);  sk += __shfl_xor(sk, 4);
    sq += __shfl_xor(sq, 8);  sk += __shfl_xor(sk, 8);
    sq += __shfl_xor(sq, 16); sk += __shfl_xor(sk, 16);
    sq += __shfl_xor(sq, 32); sk += __shfl_xor(sk, 32);
    const float qs = qv / fmaxf(sqrtf(sq), 1e-12f) * qsc;
    const float ks = kv / fmaxf(sqrtf(sk), 1e-12f) * ksc;
    const size_t bhn = (size_t)bh * SEQ_ + n;
    Qs[bhn * HD_ + lane] = f2bf(qs);
    Ks[bhn * HD_ + lane] = f2bf(ks);
    vt[lane][w * 16 + i] = f2bf(vv);
  }
  __syncthreads();
#pragma unroll
  for (int r = 0; r < 16; r++) {
    const int d = w * 16 + r;
    VT[((size_t)bh * HD_ + d) * SEQ_ + n0 + lane] = vt[d][lane];
  }
}

// ---------------- flash attention: 32 q-rows/wave, direct O write (R8 struct).
// T4: TRIPLE-buffered K/V with 2-tile-deep prefetch + counted vmcnt(4)
// at the per-tile barrier (R11-verified, 59.0->56.6us). LDS 64 KB.
// XOR chunk-swizzled K/V/P; setprio around MFMA.
__global__ __launch_bounds__(256) void attn_fwd(
    const unsigned short* __restrict__ Qs, const unsigned short* __restrict__ Ks,
    const unsigned short* __restrict__ VT, const float* __restrict__ gq,
    const float* __restrict__ gk, unsigned short* __restrict__ O) {
  __shared__ __align__(16) unsigned short Kl[3][2][64][32];  // [buf][d-half][key][chunk]
  __shared__ __align__(16) unsigned short Vl[3][2][64][32];  // [buf][key-half][d][chunk]
  __shared__ __align__(16) unsigned short Pl[4][2][16 * 64]; // [wave][q16][q][key]
  const int bh = blockIdx.x, qt = blockIdx.y;
  const int w = threadIdx.x >> 6, lane = threadIdx.x & 63;
  const int quad = lane >> 4, l15 = lane & 15;
  const float M2 = 8.0f * fabsf(gq[0] * gk[0]) * 1.4426950408889634f;
  const f32x4 cin = {-M2, -M2, -M2, -M2};
  const unsigned short* Qb = Qs + (size_t)bh * SEQ_ * HD_;
  const unsigned short* Kb = Ks + (size_t)bh * SEQ_ * HD_;
  const unsigned short* Vb = VT + (size_t)bh * HD_ * SEQ_;
  const int q0 = qt * 128 + w * 32;
  bf16x8 qa[2][2];
#pragma unroll
  for (int q16 = 0; q16 < 2; q16++) {
    qa[q16][0] = *(const bf16x8*)&Qb[(q0 + q16 * 16 + l15) * HD_ + quad * 8];
    qa[q16][1] = *(const bf16x8*)&Qb[(q0 + q16 * 16 + l15) * HD_ + 32 + quad * 8];
  }

  const int csw = ((lane & 3) ^ ((lane >> 3) & 3)) * 8;
  const unsigned short* gsrc[4];
  unsigned short* ldst[4];  // buffer-0 base; buffer b at +b*4096 shorts
  int gstep[4];
#pragma unroll
  for (int i = 0; i < 4; i++) {
    const int idx = w * 4 + i;
    if (idx < 8) {
      const int kc = idx >> 2, kh = idx & 3;
      ldst[i] = &Kl[0][kc][kh * 16][0];
      gsrc[i] = &Kb[(size_t)(kh * 16 + (lane >> 2)) * HD_ + kc * 32 + csw];
      gstep[i] = 64 * HD_;
    } else {
      const int j = idx - 8;
      const int kc = j >> 2, dh = j & 3;
      ldst[i] = &Vl[0][kc][dh * 16][0];
      gsrc[i] = &Vb[(size_t)(dh * 16 + (lane >> 2)) * SEQ_ + kc * 32 + csw];
      gstep[i] = 64;
    }
  }

  f32x4 o[2][4];
  float lacc[2] = {0.0f, 0.0f};
#pragma unroll
  for (int q16 = 0; q16 < 2; q16++)
#pragma unroll
    for (int c = 0; c < 4; c++) o[q16][c] = f32x4{0.f, 0.f, 0.f, 0.f};
  const int qsw = (quad ^ ((l15 >> 1) & 3)) * 8;
  const int psw = l15 & 7;

  const int NT = SEQ_ / 64;
  // prologue: stage tiles 0 and 1 into bufs 0 and 1
#pragma unroll
  for (int i = 0; i < 4; i++) {
    gload_lds16(gsrc[i], ldst[i]);
    gsrc[i] += gstep[i];
  }
#pragma unroll
  for (int i = 0; i < 4; i++) {
    gload_lds16(gsrc[i], ldst[i] + 4096);
    gsrc[i] += gstep[i];
  }
  vm_wait4();  // tile 0 (oldest 4) landed; tile 1's may fly
  __syncthreads();

  int cur = 0;
  for (int kt = 0; kt < NT; kt++) {
    const bool more = (kt + 2 < NT);
    if (more) {
      int nb = cur + 2; if (nb >= 3) nb -= 3;
      const int nofs = nb * 4096;
#pragma unroll
      for (int i = 0; i < 4; i++) {
        gload_lds16(gsrc[i], ldst[i] + nofs);
        gsrc[i] += gstep[i];
      }
    }
    const unsigned short* K0 = &Kl[cur][0][0][0];
    const unsigned short* K1 = &Kl[cur][1][0][0];
    const unsigned short* V0 = &Vl[cur][0][0][0];
    const unsigned short* V1 = &Vl[cur][1][0][0];
    // S^T[key][q] (pre-shifted by -M2), both q16 sub-blocks share K-frags
    f32x4 st[2][4];
    __builtin_amdgcn_s_setprio(1);
#pragma unroll
    for (int kn = 0; kn < 4; kn++) {
      const bf16x8 kf0 = *(const bf16x8*)&K0[(kn * 16 + l15) * 32 + qsw];
      const bf16x8 kf1 = *(const bf16x8*)&K1[(kn * 16 + l15) * 32 + qsw];
      st[0][kn] = __builtin_amdgcn_mfma_f32_16x16x32_bf16(kf0, qa[0][0], cin, 0, 0, 0);
      st[0][kn] = __builtin_amdgcn_mfma_f32_16x16x32_bf16(kf1, qa[0][1], st[0][kn], 0, 0, 0);
      st[1][kn] = __builtin_amdgcn_mfma_f32_16x16x32_bf16(kf0, qa[1][0], cin, 0, 0, 0);
      st[1][kn] = __builtin_amdgcn_mfma_f32_16x16x32_bf16(kf1, qa[1][1], st[1][kn], 0, 0, 0);
    }
    __builtin_amdgcn_s_setprio(0);
    // softmax numerators into per-wave dual P buffers
#pragma unroll
    for (int q16 = 0; q16 < 2; q16++) {
      unsigned short* Pw = &Pl[w][q16][0];
#pragma unroll
      for (int kn = 0; kn < 4; kn++) {
        const float p0 = ex2(st[q16][kn][0]);
        const float p1 = ex2(st[q16][kn][1]);
        const float p2 = ex2(st[q16][kn][2]);
        const float p3 = ex2(st[q16][kn][3]);
        lacc[q16] += (p0 + p1) + (p2 + p3);
        uint2 pk;
        pk.x = pk_bf2(p0, p1);
        pk.y = pk_bf2(p2, p3);
        *(uint2*)&Pw[l15 * 64 + (((kn * 2 + (quad >> 1)) ^ psw) * 8) + (quad & 1) * 4] = pk;
      }
    }
    lgkm_drain();
    bf16x8 pa[2][2];
#pragma unroll
    for (int q16 = 0; q16 < 2; q16++) {
      pa[q16][0] = *(const bf16x8*)&Pl[w][q16][l15 * 64 + ((quad ^ psw) * 8)];
      pa[q16][1] = *(const bf16x8*)&Pl[w][q16][l15 * 64 + (((4 + quad) ^ psw) * 8)];
    }
    __builtin_amdgcn_s_setprio(1);
#pragma unroll
    for (int c = 0; c < 4; c++) {
      const bf16x8 vf0 = *(const bf16x8*)&V0[(c * 16 + l15) * 32 + qsw];
      const bf16x8 vf1 = *(const bf16x8*)&V1[(c * 16 + l15) * 32 + qsw];
      o[0][c] = __builtin_amdgcn_mfma_f32_16x16x32_bf16(pa[0][0], vf0, o[0][c], 0, 0, 0);
      o[0][c] = __builtin_amdgcn_mfma_f32_16x16x32_bf16(pa[0][1], vf1, o[0][c], 0, 0, 0);
      o[1][c] = __builtin_amdgcn_mfma_f32_16x16x32_bf16(pa[1][0], vf0, o[1][c], 0, 0, 0);
      o[1][c] = __builtin_amdgcn_mfma_f32_16x16x32_bf16(pa[1][1], vf1, o[1][c], 0, 0, 0);
    }
    __builtin_amdgcn_s_setprio(0);
    if (more) vm_wait4(); else vm_drain();
    __syncthreads();
    cur = (cur == 2) ? 0 : cur + 1;
  }

  const int b = bh >> 4, h = bh & 15;
#pragma unroll
  for (int q16 = 0; q16 < 2; q16++) {
    float l = lacc[q16];
    l += __shfl_xor(l, 16);
    l += __shfl_xor(l, 32);
    const float linv = 1.0f / l;
    float lr[4];
#pragma unroll
    for (int r = 0; r < 4; r++) lr[r] = __shfl(linv, quad * 4 + r);
#pragma unroll
    for (int c = 0; c < 4; c++)
#pragma unroll
      for (int r = 0; r < 4; r++) {
        const int row = q0 + q16 * 16 + quad * 4 + r;
        O[((size_t)(b * SEQ_ + row)) * DIM_ + h * 64 + c * 16 + l15] =
            f2bf(o[q16][c][r] * lr[r]);
      }
  }
}

extern "C" void kernel_launch(void* const* d_in, const int* in_sizes, int n_in,
                              void* d_out, int out_size, void* d_ws, size_t ws_size,
                              hipStream_t stream) {
  const float* x      = (const float*)d_in[0];
  const float* w_qkv  = (const float*)d_in[1];
  const float* b_qkv  = (const float*)d_in[2];
  const float* w_proj = (const float*)d_in[3];
  const float* b_proj = (const float*)d_in[4];
  const float* g1     = (const float*)d_in[5];
  const float* g2     = (const float*)d_in[6];
  const float* gq     = (const float*)d_in[7];
  const float* gk     = (const float*)d_in[8];
  const float* w_fc1  = (const float*)d_in[9];
  const float* b_fc1  = (const float*)d_in[10];
  const float* w_fc2  = (const float*)d_in[11];
  const float* b_fc2  = (const float*)d_in[12];
  float* out = (float*)d_out;

  char* p = (char*)d_ws;
  auto alloc = [&](size_t bytes) {
    char* r = p;
    p += (bytes + 255) & ~(size_t)255;
    return r;
  };
  const size_t MB = 1ull << 20;
  unsigned short* wqkvT  = (unsigned short*)alloc(3072ull * 1024 * 2);
  unsigned short* wprojT = (unsigned short*)alloc(1024ull * 1024 * 2);
  unsigned short* wfc1T  = (unsigned short*)alloc(4096ull * 1024 * 2);
  unsigned short* wfc2T  = (unsigned short*)alloc(1024ull * 4096 * 2);
  unsigned short* h1     = (unsigned short*)alloc(4096ull * 1024 * 2);  // also Obuf
  unsigned short* QsB = (unsigned short*)alloc(32ull * SEQ_ * HD_ * 2);
  unsigned short* KsB = (unsigned short*)alloc(32ull * SEQ_ * HD_ * 2);
  unsigned short* VTB = (unsigned short*)alloc(32ull * SEQ_ * HD_ * 2);
  float* x2 = (float*)alloc(4096ull * 1024 * 4);
  unsigned short* h2 = (unsigned short*)alloc(4096ull * 1024 * 2);
  char* big = p;
  const size_t rem = ws_size - (size_t)(p - (char*)d_ws);
  unsigned short* qkvb = (unsigned short*)big;
  unsigned short* h3   = (unsigned short*)big;
  float* proj_part = (float*)big;
  float* fc2_part  = (float*)(big + 32 * MB);
  const int S_pr  = rem >= 64 * MB ? 2 : 1;
  const int S_fc2 = rem >= 96 * MB ? 4 : (rem >= 64 * MB ? 2 : 1);
  unsigned short* Obuf = h1;
  const size_t MN = 4096ull * 1024;

  transpose_cvt<<<dim3(3072 / 32, 1024 / 32), 256, 0, stream>>>(w_qkv, wqkvT, 1024, 3072);
  transpose_cvt<<<dim3(1024 / 32, 1024 / 32), 256, 0, stream>>>(w_proj, wprojT, 1024, 1024);
  transpose_cvt<<<dim3(4096 / 32, 1024 / 32), 256, 0, stream>>>(w_fc1, wfc1T, 1024, 4096);
  transpose_cvt<<<dim3(1024 / 32, 4096 / 32), 256, 0, stream>>>(w_fc2, wfc2T, 4096, 1024);
  rmsnorm_k<<<4096, 256, 0, stream>>>(x, g1, h1);
  gemm_bf16<0><<<dim3(3072 / 128, 4096 / 128), 256, 0, stream>>>(
      h1, wqkvT, b_qkv, nullptr, qkvb, 4096, 3072, 1024);
  qkv_post<<<dim3(32, 32), 256, 0, stream>>>(qkvb, gq, gk, QsB, KsB, VTB);
  attn_fwd<<<dim3(32, 16), 256, 0, stream>>>(QsB, KsB, VTB, gq, gk, Obuf);
  if (S_pr > 1) {
    gemm_bf16<3><<<dim3(1024 / 128, 4096 / 128, S_pr), 256, 0, stream>>>(
        Obuf, wprojT, b_proj, nullptr, proj_part, 4096, 1024, 1024);
    reduce_splitk<<<(MN / 4 + 255) / 256, 256, 0, stream>>>(
        proj_part, S_pr, x, b_proj, x2, 1024, MN);
  } else {
    gemm_bf16<1><<<dim3(1024 / 128, 4096 / 128), 256, 0, stream>>>(
        Obuf, wprojT, b_proj, x, x2, 4096, 1024, 1024);
  }
  rmsnorm_k<<<4096, 256, 0, stream>>>(x2, g2, h2);
  gemm_bf16<2><<<dim3(4096 / 128, 4096 / 128), 256, 0, stream>>>(
      h2, wfc1T, b_fc1, nullptr, h3, 4096, 4096, 1024);
  if (S_fc2 > 1) {
    gemm_bf16<3><<<dim3(1024 / 128, 4096 / 128, S_fc2), 256, 0, stream>>>(
        h3, wfc2T, b_fc2, nullptr, fc2_part, 4096, 1024, 4096);
    reduce_splitk<<<(MN / 4 + 255) / 256, 256, 0, stream>>>(
        fc2_part, S_fc2, x2, b_fc2, out, 1024, MN);
  } else {
    gemm_bf16<1><<<dim3(1024 / 128, 4096 / 128), 256, 0, stream>>>(
        h3, wfc2T, b_fc2, x2, out, 4096, 1024, 4096);
  }
}

// Round 14
// 336.845 us; speedup vs baseline: 1.1470x; 1.0756x over previous
//
#include <hip/hip_runtime.h>
#include <stdint.h>

#define SEQ_ 2048
#define DIM_ 1024
#define HD_ 64
#define NH_ 16

typedef __bf16 bf16x8 __attribute__((ext_vector_type(8)));
typedef float f32x4 __attribute__((ext_vector_type(4)));
typedef __attribute__((address_space(1))) unsigned int as1_uint;
typedef __attribute__((address_space(3))) unsigned int as3_uint;

__device__ __forceinline__ unsigned short f2bf(float f) {
  unsigned u = __builtin_bit_cast(unsigned, f);
  u += 0x7fffu + ((u >> 16) & 1u);
  return (unsigned short)(u >> 16);
}
__device__ __forceinline__ float bf2f(unsigned short u) {
  return __builtin_bit_cast(float, ((unsigned)u) << 16);
}
// pack two f32 -> two bf16 (truncate) in ONE v_perm_b32
__device__ __forceinline__ unsigned pk_bf2(float lo, float hi) {
  return __builtin_amdgcn_perm(__builtin_bit_cast(unsigned, hi),
                               __builtin_bit_cast(unsigned, lo), 0x07060302u);
}
// single-instruction 2^x
__device__ __forceinline__ float ex2(float x) {
  float r;
  asm("v_exp_f32 %0, %1" : "=v"(r) : "v"(x));
  return r;
}
// explicit waits: compiler does NOT reliably emit vmcnt before s_barrier for
// cross-backedge global_load_lds deps (R4 race) — we control them manually.
__device__ __forceinline__ void vm_drain() {
  asm volatile("s_waitcnt vmcnt(0)" ::: "memory");
}
// counted wait (T4): helps only low-occupancy serial-chain kernels (attn);
// regresses the high-occupancy 2-phase GEMM (R12).
__device__ __forceinline__ void vm_wait4() {
  asm volatile("s_waitcnt vmcnt(4)" ::: "memory");
}
__device__ __forceinline__ void lgkm_drain() {
  asm volatile("s_waitcnt lgkmcnt(0)" ::: "memory");
}

// async global->LDS, 16B per lane. LDS dest is wave-uniform base + lane*16.
__device__ __forceinline__ void gload_lds16(const void* g, void* l) {
  __builtin_amdgcn_global_load_lds(
      reinterpret_cast<as1_uint*>(reinterpret_cast<uintptr_t>(g)),
      reinterpret_cast<as3_uint*>(
          static_cast<unsigned int>(reinterpret_cast<uintptr_t>(l))),
      16, 0, 0);
}

// ---------------- weight transpose + fp32->bf16 convert: Wt[n][k] = W[k][n]
__global__ __launch_bounds__(256) void transpose_cvt(
    const float* __restrict__ W, unsigned short* __restrict__ Wt, int K, int N) {
  __shared__ float t[32][33];
  const int tx = threadIdx.x & 31, ty = threadIdx.x >> 5;  // ty 0..7
  const int n0 = blockIdx.x * 32, k0 = blockIdx.y * 32;
#pragma unroll
  for (int i = 0; i < 4; i++)
    t[ty + i * 8][tx] = W[(size_t)(k0 + ty + i * 8) * N + n0 + tx];
  __syncthreads();
#pragma unroll
  for (int i = 0; i < 4; i++)
    Wt[(size_t)(n0 + ty + i * 8) * K + k0 + tx] = f2bf(t[tx][ty + i * 8]);
}

// ---------------- rmsnorm over DIM: out = x/max(||x||,eps)*32*g  (bf16)
__global__ __launch_bounds__(256) void rmsnorm_k(
    const float* __restrict__ x, const float* __restrict__ g,
    unsigned short* __restrict__ out) {
  const int row = blockIdx.x;
  const float4* xr = (const float4*)(x + (size_t)row * DIM_);
  float4 v = xr[threadIdx.x];
  float ss = v.x * v.x + v.y * v.y + v.z * v.z + v.w * v.w;
  ss += __shfl_xor(ss, 1);  ss += __shfl_xor(ss, 2);  ss += __shfl_xor(ss, 4);
  ss += __shfl_xor(ss, 8);  ss += __shfl_xor(ss, 16); ss += __shfl_xor(ss, 32);
  __shared__ float red[4];
  if ((threadIdx.x & 63) == 0) red[threadIdx.x >> 6] = ss;
  __syncthreads();
  float tot = red[0] + red[1] + red[2] + red[3];
  float sc = 32.0f * g[0] / fmaxf(sqrtf(tot), 1e-12f);
  unsigned short* orow = out + (size_t)row * DIM_;
  const int b4 = threadIdx.x * 4;
  orow[b4 + 0] = f2bf(v.x * sc);
  orow[b4 + 1] = f2bf(v.y * sc);
  orow[b4 + 2] = f2bf(v.z * sc);
  orow[b4 + 3] = f2bf(v.w * sc);
}

// ---------------- GEMM: C[M,N] = A[M,K]@Bt[N,K]^T, split-K over gridDim.z
// R13-PROVEN core: BK=32 double-buffer (32 KB LDS), chunk-XOR swizzled LDS
// (0 conflicts), issue-early staging + explicit vmcnt(0) drain + ONE barrier
// per K-step, XCD-chunked bijective blockIdx swizzle.
// EPI: 0 = bias, bf16 out; 1 = bias + residual, f32 out;
//      2 = bias + gelu, bf16 out; 3 = raw f32 partial at z-offset (no bias)
//      4 = qkv fused: Q/K head-norm written to Qs/Ks (wave tile = one head);
//          V columns stored to Cout as EPI0.
template <int EPI>
__global__ __launch_bounds__(256, 2) void gemm_bf16(
    const unsigned short* __restrict__ A, const unsigned short* __restrict__ Bt,
    const float* __restrict__ bias, const float* __restrict__ res,
    void* __restrict__ Cout, int M, int N, int K,
    const float* __restrict__ gq, const float* __restrict__ gk,
    unsigned short* __restrict__ Qs, unsigned short* __restrict__ Ks) {
  __shared__ __align__(16) unsigned short As[2][128 * 32];
  __shared__ __align__(16) unsigned short Bs[2][128 * 32];
  const int tid = threadIdx.x;
  const int w = tid >> 6, lane = tid & 63;
  const int wm = w >> 1, wn = w & 1;
  const int quad = lane >> 4, l15 = lane & 15;

  // XCD-chunked bijective swizzle (T1)
  const unsigned gx = gridDim.x, gy = gridDim.y;
  const unsigned nwg = gx * gy * gridDim.z;
  const unsigned p0 = blockIdx.x + gx * (blockIdx.y + gy * blockIdx.z);
  const unsigned lg = (p0 & 7) * (nwg >> 3) + (p0 >> 3);
  const int bn = lg % gx;
  const unsigned t1 = lg / gx;
  const int bm = t1 % gy;
  const int bz = t1 / gy;

  const int Kchunk = K / gridDim.z;
  const int kbeg = bz * Kchunk;

  f32x4 acc[4][4];
#pragma unroll
  for (int i = 0; i < 4; i++)
#pragma unroll
    for (int j = 0; j < 4; j++) acc[i][j] = f32x4{0.f, 0.f, 0.f, 0.f};

  const int r0 = w * 16 + (lane >> 2);
  const int csw = ((lane & 3) ^ ((lane >> 3) & 3)) * 8;
  const unsigned short* gA0 = A + (size_t)(bm * 128 + r0) * K + kbeg + csw;
  const unsigned short* gA1 = gA0 + (size_t)64 * K;
  const unsigned short* gB0 = Bt + (size_t)(bn * 128 + r0) * K + kbeg + csw;
  const unsigned short* gB1 = gB0 + (size_t)64 * K;
  const int lofs = w * 512;

  auto stage = [&](int buf) {
    gload_lds16(gA0, &As[buf][lofs]);
    gload_lds16(gA1, &As[buf][2048 + lofs]);
    gload_lds16(gB0, &Bs[buf][lofs]);
    gload_lds16(gB1, &Bs[buf][2048 + lofs]);
    gA0 += 32; gA1 += 32; gB0 += 32; gB1 += 32;
  };

  const int qsw = (quad ^ ((l15 >> 1) & 3)) * 8;

  stage(0);
  vm_drain();
  __syncthreads();
  const int niter = Kchunk / 32;
  for (int kk = 0; kk < niter; kk++) {
    const int cur = kk & 1;
    if (kk + 1 < niter) stage(cur ^ 1);  // issue-early into other buffer
    bf16x8 af[4], bfr[4];
#pragma unroll
    for (int i = 0; i < 4; i++) {
      af[i]  = *(const bf16x8*)&As[cur][(wm * 64 + i * 16 + l15) * 32 + qsw];
      bfr[i] = *(const bf16x8*)&Bs[cur][(wn * 64 + i * 16 + l15) * 32 + qsw];
    }
#pragma unroll
    for (int i = 0; i < 4; i++)
#pragma unroll
      for (int j = 0; j < 4; j++)
        acc[i][j] = __builtin_amdgcn_mfma_f32_16x16x32_bf16(af[i], bfr[j], acc[i][j], 0, 0, 0);
    vm_drain();
    __syncthreads();
  }

  const int rowb = bm * 128 + wm * 64;
  const int colb = bn * 128 + wn * 64;

  if (EPI == 4 && bn < 16) {
    // ---- fused per-head L2 norm: this wave's 64 cols == one head ----
    const bool isK = (bn >= 8);
    const int h = (bn - (isK ? 8 : 0)) * 2 + wn;
    const float sc = isK ? (8.0f * gk[0]) : (1.4426950408889634f * gq[0]);
    unsigned short* Dst = isK ? Ks : Qs;
    float bv[4];
#pragma unroll
    for (int j = 0; j < 4; j++) bv[j] = bias[colb + j * 16 + l15];
#pragma unroll
    for (int i = 0; i < 4; i++)
#pragma unroll
      for (int j = 0; j < 4; j++)
#pragma unroll
        for (int r = 0; r < 4; r++) acc[i][j][r] += bv[j];
#pragma unroll
    for (int i = 0; i < 4; i++) {
#pragma unroll
      for (int r = 0; r < 4; r++) {
        float ss = acc[i][0][r] * acc[i][0][r] + acc[i][1][r] * acc[i][1][r] +
                   acc[i][2][r] * acc[i][2][r] + acc[i][3][r] * acc[i][3][r];
        ss += __shfl_xor(ss, 1); ss += __shfl_xor(ss, 2);
        ss += __shfl_xor(ss, 4); ss += __shfl_xor(ss, 8);
        const float scale = sc / fmaxf(sqrtf(ss), 1e-12f);
        const int R = rowb + i * 16 + quad * 4 + r;
        const int b = R >> 11, n = R & 2047;
        unsigned short* orow =
            Dst + ((size_t)(b * 16 + h) * SEQ_ + n) * HD_;
#pragma unroll
        for (int j = 0; j < 4; j++)
          orow[j * 16 + l15] = f2bf(acc[i][j][r] * scale);
      }
    }
    return;
  }

  float* Cz = (float*)Cout + (size_t)bz * M * N;  // EPI3 partial slab
  const float kg1 = -2.0f * 1.4426950408889634f * 0.7978845608028654f;
  const float kg2 = kg1 * 0.044715f;
#pragma unroll
  for (int i = 0; i < 4; i++) {
#pragma unroll
    for (int j = 0; j < 4; j++) {
      const int col = colb + j * 16 + l15;
      const float bv = (EPI == 3) ? 0.0f : bias[col];
#pragma unroll
      for (int r = 0; r < 4; r++) {
        const int row = rowb + i * 16 + quad * 4 + r;
        const size_t idx = (size_t)row * N + col;
        float v = acc[i][j][r] + bv;
        if (EPI == 0 || EPI == 4) {
          ((unsigned short*)Cout)[idx] = f2bf(v);
        } else if (EPI == 1) {
          ((float*)Cout)[idx] = v + res[idx];
        } else if (EPI == 2) {
          const float u = v * (kg1 + kg2 * v * v);
          const float g = v * __builtin_amdgcn_rcpf(1.0f + ex2(u));
          ((unsigned short*)Cout)[idx] = f2bf(g);
        } else {
          Cz[idx] = v;
        }
      }
    }
  }
}

// ---------------- split-K reduce: out = res + bias + sum_z part[z]
__global__ __launch_bounds__(256) void reduce_splitk(
    const float* __restrict__ part, int S, const float* __restrict__ res,
    const float* __restrict__ bias, float* __restrict__ out, int N, size_t MN) {
  const size_t n4 = MN >> 2;
  const size_t i = (size_t)blockIdx.x * 256 + threadIdx.x;
  if (i >= n4) return;
  float4 a = ((const float4*)res)[i];
  float4 b = ((const float4*)bias)[i % (size_t)(N >> 2)];
  float sx = a.x + b.x, sy = a.y + b.y, sz = a.z + b.z, sw = a.w + b.w;
  for (int z = 0; z < S; z++) {
    float4 p = ((const float4*)part)[z * n4 + i];
    sx += p.x; sy += p.y; sz += p.z; sw += p.w;
  }
  ((float4*)out)[i] = make_float4(sx, sy, sz, sw);
}

// ---------------- fused split-K reduce + rmsnorm: one block = one 1024-row.
// x2 = res + bias + sum_z part[z]; h2 = rmsnorm(x2)*g (bf16).
__global__ __launch_bounds__(256) void reduce_rms(
    const float* __restrict__ part, int S, const float* __restrict__ res,
    const float* __restrict__ bias, float* __restrict__ x2,
    unsigned short* __restrict__ h2, const float* __restrict__ g) {
  const size_t i = (size_t)blockIdx.x * 256 + threadIdx.x;
  const size_t n4 = 4096ull * 256;  // MN/4
  float4 a = ((const float4*)res)[i];
  float4 b = ((const float4*)bias)[threadIdx.x];
  float sx = a.x + b.x, sy = a.y + b.y, sz = a.z + b.z, sw = a.w + b.w;
  for (int z = 0; z < S; z++) {
    float4 p = ((const float4*)part)[z * n4 + i];
    sx += p.x; sy += p.y; sz += p.z; sw += p.w;
  }
  ((float4*)x2)[i] = make_float4(sx, sy, sz, sw);
  float ss = sx * sx + sy * sy + sz * sz + sw * sw;
  ss += __shfl_xor(ss, 1);  ss += __shfl_xor(ss, 2);  ss += __shfl_xor(ss, 4);
  ss += __shfl_xor(ss, 8);  ss += __shfl_xor(ss, 16); ss += __shfl_xor(ss, 32);
  __shared__ float red[4];
  if ((threadIdx.x & 63) == 0) red[threadIdx.x >> 6] = ss;
  __syncthreads();
  const float tot = red[0] + red[1] + red[2] + red[3];
  const float sc = 32.0f * g[0] / fmaxf(sqrtf(tot), 1e-12f);
  unsigned short* orow = h2 + (size_t)blockIdx.x * DIM_ + threadIdx.x * 4;
  orow[0] = f2bf(sx * sc);
  orow[1] = f2bf(sy * sc);
  orow[2] = f2bf(sz * sc);
  orow[3] = f2bf(sw * sc);
}

// ---------------- V-only postprocess: transpose V through LDS (coalesced)
__global__ __launch_bounds__(256) void v_post(
    const unsigned short* __restrict__ qkv, unsigned short* __restrict__ VT) {
  __shared__ unsigned short vt[64][66];
  const int bh = blockIdx.x;  // b*16+h
  const int n0 = blockIdx.y * 64;
  const int b = bh >> 4, h = bh & 15;
  const int w = threadIdx.x >> 6, lane = threadIdx.x & 63;
  for (int i = 0; i < 16; i++) {
    const int n = n0 + w * 16 + i;
    vt[lane][w * 16 + i] =
        qkv[(size_t)(b * SEQ_ + n) * 3072 + 2048 + h * 64 + lane];
  }
  __syncthreads();
#pragma unroll
  for (int r = 0; r < 16; r++) {
    const int d = w * 16 + r;
    VT[((size_t)bh * HD_ + d) * SEQ_ + n0 + lane] = vt[d][lane];
  }
}

// ---------------- flash attention: 32 q-rows/wave, direct O write.
// T4: TRIPLE-buffered K/V with 2-tile-deep prefetch + counted vmcnt(4)
// (R11-verified). XOR chunk-swizzled K/V/P; setprio around MFMA.
__global__ __launch_bounds__(256) void attn_fwd(
    const unsigned short* __restrict__ Qs, const unsigned short* __restrict__ Ks,
    const unsigned short* __restrict__ VT, const float* __restrict__ gq,
    const float* __restrict__ gk, unsigned short* __restrict__ O) {
  __shared__ __align__(16) unsigned short Kl[3][2][64][32];  // [buf][d-half][key][chunk]
  __shared__ __align__(16) unsigned short Vl[3][2][64][32];  // [buf][key-half][d][chunk]
  __shared__ __align__(16) unsigned short Pl[4][2][16 * 64]; // [wave][q16][q][key]
  const int bh = blockIdx.x, qt = blockIdx.y;
  const int w = threadIdx.x >> 6, lane = threadIdx.x & 63;
  const int quad = lane >> 4, l15 = lane & 15;
  const float M2 = 8.0f * fabsf(gq[0] * gk[0]) * 1.4426950408889634f;
  const f32x4 cin = {-M2, -M2, -M2, -M2};
  const unsigned short* Qb = Qs + (size_t)bh * SEQ_ * HD_;
  const unsigned short* Kb = Ks + (size_t)bh * SEQ_ * HD_;
  const unsigned short* Vb = VT + (size_t)bh * HD_ * SEQ_;
  const int q0 = qt * 128 + w * 32;
  bf16x8 qa[2][2];
#pragma unroll
  for (int q16 = 0; q16 < 2; q16++) {
    qa[q16][0] = *(const bf16x8*)&Qb[(q0 + q16 * 16 + l15) * HD_ + quad * 8];
    qa[q16][1] = *(const bf16x8*)&Qb[(q0 + q16 * 16 + l15) * HD_ + 32 + quad * 8];
  }

  const int csw = ((lane & 3) ^ ((lane >> 3) & 3)) * 8;
  const unsigned short* gsrc[4];
  unsigned short* ldst[4];  // buffer-0 base; buffer b at +b*4096 shorts
  int gstep[4];
#pragma unroll
  for (int i = 0; i < 4; i++) {
    const int idx = w * 4 + i;
    if (idx < 8) {
      const int kc = idx >> 2, kh = idx & 3;
      ldst[i] = &Kl[0][kc][kh * 16][0];
      gsrc[i] = &Kb[(size_t)(kh * 16 + (lane >> 2)) * HD_ + kc * 32 + csw];
      gstep[i] = 64 * HD_;
    } else {
      const int j = idx - 8;
      const int kc = j >> 2, dh = j & 3;
      ldst[i] = &Vl[0][kc][dh * 16][0];
      gsrc[i] = &Vb[(size_t)(dh * 16 + (lane >> 2)) * SEQ_ + kc * 32 + csw];
      gstep[i] = 64;
    }
  }

  f32x4 o[2][4];
  float lacc[2] = {0.0f, 0.0f};
#pragma unroll
  for (int q16 = 0; q16 < 2; q16++)
#pragma unroll
    for (int c = 0; c < 4; c++) o[q16][c] = f32x4{0.f, 0.f, 0.f, 0.f};
  const int qsw = (quad ^ ((l15 >> 1) & 3)) * 8;
  const int psw = l15 & 7;

  const int NT = SEQ_ / 64;
  // prologue: stage tiles 0 and 1 into bufs 0 and 1
#pragma unroll
  for (int i = 0; i < 4; i++) {
    gload_lds16(gsrc[i], ldst[i]);
    gsrc[i] += gstep[i];
  }
#pragma unroll
  for (int i = 0; i < 4; i++) {
    gload_lds16(gsrc[i], ldst[i] + 4096);
    gsrc[i] += gstep[i];
  }
  vm_wait4();  // tile 0 (oldest 4) landed; tile 1's may fly
  __syncthreads();

  int cur = 0;
  for (int kt = 0; kt < NT; kt++) {
    const bool more = (kt + 2 < NT);
    if (more) {
      int nb = cur + 2; if (nb >= 3) nb -= 3;
      const int nofs = nb * 4096;
#pragma unroll
      for (int i = 0; i < 4; i++) {
        gload_lds16(gsrc[i], ldst[i] + nofs);
        gsrc[i] += gstep[i];
      }
    }
    const unsigned short* K0 = &Kl[cur][0][0][0];
    const unsigned short* K1 = &Kl[cur][1][0][0];
    const unsigned short* V0 = &Vl[cur][0][0][0];
    const unsigned short* V1 = &Vl[cur][1][0][0];
    f32x4 st[2][4];
    __builtin_amdgcn_s_setprio(1);
#pragma unroll
    for (int kn = 0; kn < 4; kn++) {
      const bf16x8 kf0 = *(const bf16x8*)&K0[(kn * 16 + l15) * 32 + qsw];
      const bf16x8 kf1 = *(const bf16x8*)&K1[(kn * 16 + l15) * 32 + qsw];
      st[0][kn] = __builtin_amdgcn_mfma_f32_16x16x32_bf16(kf0, qa[0][0], cin, 0, 0, 0);
      st[0][kn] = __builtin_amdgcn_mfma_f32_16x16x32_bf16(kf1, qa[0][1], st[0][kn], 0, 0, 0);
      st[1][kn] = __builtin_amdgcn_mfma_f32_16x16x32_bf16(kf0, qa[1][0], cin, 0, 0, 0);
      st[1][kn] = __builtin_amdgcn_mfma_f32_16x16x32_bf16(kf1, qa[1][1], st[1][kn], 0, 0, 0);
    }
    __builtin_amdgcn_s_setprio(0);
#pragma unroll
    for (int q16 = 0; q16 < 2; q16++) {
      unsigned short* Pw = &Pl[w][q16][0];
#pragma unroll
      for (int kn = 0; kn < 4; kn++) {
        const float p0 = ex2(st[q16][kn][0]);
        const float p1 = ex2(st[q16][kn][1]);
        const float p2 = ex2(st[q16][kn][2]);
        const float p3 = ex2(st[q16][kn][3]);
        lacc[q16] += (p0 + p1) + (p2 + p3);
        uint2 pk;
        pk.x = pk_bf2(p0, p1);
        pk.y = pk_bf2(p2, p3);
        *(uint2*)&Pw[l15 * 64 + (((kn * 2 + (quad >> 1)) ^ psw) * 8) + (quad & 1) * 4] = pk;
      }
    }
    lgkm_drain();
    bf16x8 pa[2][2];
#pragma unroll
    for (int q16 = 0; q16 < 2; q16++) {
      pa[q16][0] = *(const bf16x8*)&Pl[w][q16][l15 * 64 + ((quad ^ psw) * 8)];
      pa[q16][1] = *(const bf16x8*)&Pl[w][q16][l15 * 64 + (((4 + quad) ^ psw) * 8)];
    }
    __builtin_amdgcn_s_setprio(1);
#pragma unroll
    for (int c = 0; c < 4; c++) {
      const bf16x8 vf0 = *(const bf16x8*)&V0[(c * 16 + l15) * 32 + qsw];
      const bf16x8 vf1 = *(const bf16x8*)&V1[(c * 16 + l15) * 32 + qsw];
      o[0][c] = __builtin_amdgcn_mfma_f32_16x16x32_bf16(pa[0][0], vf0, o[0][c], 0, 0, 0);
      o[0][c] = __builtin_amdgcn_mfma_f32_16x16x32_bf16(pa[0][1], vf1, o[0][c], 0, 0, 0);
      o[1][c] = __builtin_amdgcn_mfma_f32_16x16x32_bf16(pa[1][0], vf0, o[1][c], 0, 0, 0);
      o[1][c] = __builtin_amdgcn_mfma_f32_16x16x32_bf16(pa[1][1], vf1, o[1][c], 0, 0, 0);
    }
    __builtin_amdgcn_s_setprio(0);
    if (more) vm_wait4(); else vm_drain();
    __syncthreads();
    cur = (cur == 2) ? 0 : cur + 1;
  }

  const int b = bh >> 4, h = bh & 15;
#pragma unroll
  for (int q16 = 0; q16 < 2; q16++) {
    float l = lacc[q16];
    l += __shfl_xor(l, 16);
    l += __shfl_xor(l, 32);
    const float linv = 1.0f / l;
    float lr[4];
#pragma unroll
    for (int r = 0; r < 4; r++) lr[r] = __shfl(linv, quad * 4 + r);
#pragma unroll
    for (int c = 0; c < 4; c++)
#pragma unroll
      for (int r = 0; r < 4; r++) {
        const int row = q0 + q16 * 16 + quad * 4 + r;
        O[((size_t)(b * SEQ_ + row)) * DIM_ + h * 64 + c * 16 + l15] =
            f2bf(o[q16][c][r] * lr[r]);
      }
  }
}

extern "C" void kernel_launch(void* const* d_in, const int* in_sizes, int n_in,
                              void* d_out, int out_size, void* d_ws, size_t ws_size,
                              hipStream_t stream) {
  const float* x      = (const float*)d_in[0];
  const float* w_qkv  = (const float*)d_in[1];
  const float* b_qkv  = (const float*)d_in[2];
  const float* w_proj = (const float*)d_in[3];
  const float* b_proj = (const float*)d_in[4];
  const float* g1     = (const float*)d_in[5];
  const float* g2     = (const float*)d_in[6];
  const float* gq     = (const float*)d_in[7];
  const float* gk     = (const float*)d_in[8];
  const float* w_fc1  = (const float*)d_in[9];
  const float* b_fc1  = (const float*)d_in[10];
  const float* w_fc2  = (const float*)d_in[11];
  const float* b_fc2  = (const float*)d_in[12];
  float* out = (float*)d_out;

  char* p = (char*)d_ws;
  auto alloc = [&](size_t bytes) {
    char* r = p;
    p += (bytes + 255) & ~(size_t)255;
    return r;
  };
  const size_t MB = 1ull << 20;
  unsigned short* wqkvT  = (unsigned short*)alloc(3072ull * 1024 * 2);
  unsigned short* wprojT = (unsigned short*)alloc(1024ull * 1024 * 2);
  unsigned short* wfc1T  = (unsigned short*)alloc(4096ull * 1024 * 2);
  unsigned short* wfc2T  = (unsigned short*)alloc(1024ull * 4096 * 2);
  unsigned short* h1     = (unsigned short*)alloc(4096ull * 1024 * 2);  // also Obuf
  unsigned short* QsB = (unsigned short*)alloc(32ull * SEQ_ * HD_ * 2);
  unsigned short* KsB = (unsigned short*)alloc(32ull * SEQ_ * HD_ * 2);
  unsigned short* VTB = (unsigned short*)alloc(32ull * SEQ_ * HD_ * 2);
  float* x2 = (float*)alloc(4096ull * 1024 * 4);
  unsigned short* h2 = (unsigned short*)alloc(4096ull * 1024 * 2);
  char* big = p;
  const size_t rem = ws_size - (size_t)(p - (char*)d_ws);
  unsigned short* qkvb = (unsigned short*)big;
  unsigned short* h3   = (unsigned short*)big;
  float* proj_part = (float*)big;
  float* fc2_part  = (float*)(big + 32 * MB);
  const int S_pr  = rem >= 64 * MB ? 2 : 1;
  const int S_fc2 = rem >= 64 * MB ? 2 : 1;  // z=2: halves partial traffic vs 4
  unsigned short* Obuf = h1;
  const size_t MN = 4096ull * 1024;

  transpose_cvt<<<dim3(3072 / 32, 1024 / 32), 256, 0, stream>>>(w_qkv, wqkvT, 1024, 3072);
  transpose_cvt<<<dim3(1024 / 32, 1024 / 32), 256, 0, stream>>>(w_proj, wprojT, 1024, 1024);
  transpose_cvt<<<dim3(4096 / 32, 1024 / 32), 256, 0, stream>>>(w_fc1, wfc1T, 1024, 4096);
  transpose_cvt<<<dim3(1024 / 32, 4096 / 32), 256, 0, stream>>>(w_fc2, wfc2T, 4096, 1024);
  rmsnorm_k<<<4096, 256, 0, stream>>>(x, g1, h1);
  // qkv GEMM with fused Q/K head-norm epilogue (EPI4); V cols -> qkvb
  gemm_bf16<4><<<dim3(3072 / 128, 4096 / 128), 256, 0, stream>>>(
      h1, wqkvT, b_qkv, nullptr, qkvb, 4096, 3072, 1024, gq, gk, QsB, KsB);
  v_post<<<dim3(32, 32), 256, 0, stream>>>(qkvb, VTB);
  attn_fwd<<<dim3(32, 16), 256, 0, stream>>>(QsB, KsB, VTB, gq, gk, Obuf);
  if (S_pr > 1) {
    gemm_bf16<3><<<dim3(1024 / 128, 4096 / 128, S_pr), 256, 0, stream>>>(
        Obuf, wprojT, b_proj, nullptr, proj_part, 4096, 1024, 1024,
        nullptr, nullptr, nullptr, nullptr);
    // fused reduce + rmsnorm2: writes x2 (f32) and h2 (bf16)
    reduce_rms<<<4096, 256, 0, stream>>>(proj_part, S_pr, x, b_proj, x2, h2, g2);
  } else {
    gemm_bf16<1><<<dim3(1024 / 128, 4096 / 128), 256, 0, stream>>>(
        Obuf, wprojT, b_proj, x, x2, 4096, 1024, 1024,
        nullptr, nullptr, nullptr, nullptr);
    rmsnorm_k<<<4096, 256, 0, stream>>>(x2, g2, h2);
  }
  gemm_bf16<2><<<dim3(4096 / 128, 4096 / 128), 256, 0, stream>>>(
      h2, wfc1T, b_fc1, nullptr, h3, 4096, 4096, 1024,
      nullptr, nullptr, nullptr, nullptr);
  if (S_fc2 > 1) {
    gemm_bf16<3><<<dim3(1024 / 128, 4096 / 128, S_fc2), 256, 0, stream>>>(
        h3, wfc2T, b_fc2, nullptr, fc2_part, 4096, 1024, 4096,
        nullptr, nullptr, nullptr, nullptr);
    reduce_splitk<<<(MN / 4 + 255) / 256, 256, 0, stream>>>(
        fc2_part, S_fc2, x2, b_fc2, out, 1024, MN);
  } else {
    gemm_bf16<1><<<dim3(1024 / 128, 4096 / 128), 256, 0, stream>>>(
        h3, wfc2T, b_fc2, x2, out, 4096, 1024, 4096,
        nullptr, nullptr, nullptr, nullptr);
  }
}